// Round 1
// baseline (336.009 us; speedup 1.0000x reference)
//
#include <hip/hip_runtime.h>
#include <math.h>

// MultiLocalCosineLinear: B=65536 rows, D=768, C=100, P=4950 pairs.
// out layout (all float32): [0..B)   = preds (class id as float)
//                           [B..3B)  = logits, row-major (B,2)
//
// One wave (64 lanes) per row; 4 waves / 256-thread block.

#define D_DIM 768
#define C_DIM 100
#define F4_PER_ROW (D_DIM / 4)   // 192
#define EPS_N 1e-12f

__device__ __forceinline__ bool vi_gt(float v0, int i0, float v1, int i1) {
    // lexicographic (value desc, index asc): "candidate 0 ranks above candidate 1"
    return (v0 > v1) || (v0 == v1 && i0 < i1);
}

__global__ __launch_bounds__(256) void mlcl_kernel(
    const float* __restrict__ x,
    const float* __restrict__ first_out,
    const float* __restrict__ weights,
    const float* __restrict__ sigma,
    float* __restrict__ out,
    int B)
{
    const int lane = threadIdx.x & 63;
    const int wave = threadIdx.x >> 6;
    const int r = blockIdx.x * 4 + wave;
    if (r >= B) return;

    // ---------- top-2 of first_out[r, 0:100] ----------
    const float* fo = first_out + (size_t)r * C_DIM;
    float e0 = fo[lane];                                   // lane < 64 < 100 always valid
    int   j1 = lane + 64;
    float e1 = (j1 < C_DIM) ? fo[j1] : -INFINITY;

    float v1, v2; int i1, i2;
    if (vi_gt(e1, j1, e0, lane)) { v1 = e1; i1 = j1;  v2 = e0; i2 = lane; }
    else                         { v1 = e0; i1 = lane; v2 = e1; i2 = j1; }

    #pragma unroll
    for (int m = 1; m < 64; m <<= 1) {
        float ov1 = __shfl_xor(v1, m, 64);
        int   oi1 = __shfl_xor(i1, m, 64);
        float ov2 = __shfl_xor(v2, m, 64);
        int   oi2 = __shfl_xor(i2, m, 64);
        if (vi_gt(ov1, oi1, v1, i1)) {
            // new top = other's top; second = best of {my top, other's second}
            float nv2; int ni2;
            if (vi_gt(v1, i1, ov2, oi2)) { nv2 = v1;  ni2 = i1; }
            else                         { nv2 = ov2; ni2 = oi2; }
            v1 = ov1; i1 = oi1; v2 = nv2; i2 = ni2;
        } else {
            // top unchanged; second = best of {my second, other's top}
            if (vi_gt(ov1, oi1, v2, i2)) { v2 = ov1; i2 = oi1; }
        }
    }
    // all lanes now agree on (i1, i2)
    const int a = min(i1, i2);
    const int b = max(i1, i2);
    const int pair = b * (b - 1) / 2 + a;

    // ---------- dots + norms over D=768 ----------
    const float4* xv = (const float4*)(x + (size_t)r * D_DIM);
    const float4* w0 = (const float4*)(weights + (size_t)pair * (2 * D_DIM));
    const float4* w1 = w0 + F4_PER_ROW;

    double xx = 0.0, d0 = 0.0, d1 = 0.0, n0 = 0.0, n1 = 0.0;
    #pragma unroll
    for (int j = 0; j < 3; ++j) {
        const int idx = lane + j * 64;
        float4 xa = xv[idx];
        float4 wa = w0[idx];
        float4 wb = w1[idx];
        xx += (double)xa.x * xa.x + (double)xa.y * xa.y + (double)xa.z * xa.z + (double)xa.w * xa.w;
        d0 += (double)xa.x * wa.x + (double)xa.y * wa.y + (double)xa.z * wa.z + (double)xa.w * wa.w;
        d1 += (double)xa.x * wb.x + (double)xa.y * wb.y + (double)xa.z * wb.z + (double)xa.w * wb.w;
        n0 += (double)wa.x * wa.x + (double)wa.y * wa.y + (double)wa.z * wa.z + (double)wa.w * wa.w;
        n1 += (double)wb.x * wb.x + (double)wb.y * wb.y + (double)wb.z * wb.z + (double)wb.w * wb.w;
    }
    #pragma unroll
    for (int m = 1; m < 64; m <<= 1) {
        xx += __shfl_xor(xx, m, 64);
        d0 += __shfl_xor(d0, m, 64);
        d1 += __shfl_xor(d1, m, 64);
        n0 += __shfl_xor(n0, m, 64);
        n1 += __shfl_xor(n1, m, 64);
    }

    if (lane == 0) {
        double s   = (double)sigma[pair];
        double inx = 1.0 / fmax(sqrt(xx), (double)EPS_N);
        double l0  = s * d0 * inx / fmax(sqrt(n0), (double)EPS_N);
        double l1  = s * d1 * inx / fmax(sqrt(n1), (double)EPS_N);
        int sel = (l1 > l0) ? 1 : 0;           // jnp.argmax: first index wins ties
        out[r] = (float)(sel ? b : a);
        out[B + 2 * r]     = (float)l0;
        out[B + 2 * r + 1] = (float)l1;
    }
}

extern "C" void kernel_launch(void* const* d_in, const int* in_sizes, int n_in,
                              void* d_out, int out_size, void* d_ws, size_t ws_size,
                              hipStream_t stream) {
    const float* x         = (const float*)d_in[0];
    const float* first_out = (const float*)d_in[1];
    const float* weights   = (const float*)d_in[2];
    const float* sigma     = (const float*)d_in[3];
    // d_in[4] = cur_stage (unused by the math)
    float* out = (float*)d_out;

    const int B = in_sizes[0] / D_DIM;   // 65536
    dim3 grid((B + 3) / 4), block(256);
    hipLaunchKernelGGL(mlcl_kernel, grid, block, 0, stream,
                       x, first_out, weights, sigma, out, B);
}

// Round 2
// 335.686 us; speedup vs baseline: 1.0010x; 1.0010x over previous
//
#include <hip/hip_runtime.h>
#include <math.h>

// MultiLocalCosineLinear: B=65536 rows, D=768, C=100, P=4950 pairs.
// out layout (all float32): [0..B)  = preds (class id as float)
//                           [B..3B) = logits, row-major (B,2)
//
// 3-kernel split (R1): the R0 single kernel was latency-bound (31% HBM,
// 35% VALU, 0 MFMA) on two serial chains per wave: top-2 shuffle merge
// gating the weight gather, and a 5-acc f64 butterfly. K1 precomputes
// weight inverse-norms, K2 precomputes the top-2 pair per row, K3 streams
// x + gathers weights with no shuffle chain ahead of the loads.

#define D_DIM 768
#define C_DIM 100
#define P_DIM 4950           // C*(C-1)/2
#define F4_PER_ROW (D_DIM / 4)   // 192
#define EPS_N 1e-12

__device__ __forceinline__ bool vi_gt(float v0, int i0, float v1, int i1) {
    // lexicographic (value desc, index asc)
    return (v0 > v1) || (v0 == v1 && i0 < i1);
}

// ---------------- K1: weight inverse norms (f64 exact) ----------------
// one wave per weight vector; 2P = 9900 vectors
__global__ __launch_bounds__(256) void norm_kernel(
    const float* __restrict__ weights,
    double* __restrict__ invn,
    int nrows)
{
    const int lane = threadIdx.x & 63;
    const int row = (blockIdx.x << 2) + (threadIdx.x >> 6);
    if (row >= nrows) return;

    const float4* wv = (const float4*)(weights + (size_t)row * D_DIM);
    double n = 0.0;
    #pragma unroll
    for (int j = 0; j < 3; ++j) {
        float4 w = wv[lane + j * 64];
        n += (double)w.x * w.x + (double)w.y * w.y
           + (double)w.z * w.z + (double)w.w * w.w;
    }
    #pragma unroll
    for (int m = 1; m < 64; m <<= 1) n += __shfl_xor(n, m, 64);
    if (lane == 0) invn[row] = 1.0 / fmax(sqrt(n), EPS_N);
}

// ---------------- K2: top-2 of first_out rows -> packed (a,b) ----------------
__global__ __launch_bounds__(256) void top2_kernel(
    const float* __restrict__ first_out,
    int* __restrict__ abbuf,
    int B)
{
    const int lane = threadIdx.x & 63;
    const int r = (blockIdx.x << 2) + (threadIdx.x >> 6);
    if (r >= B) return;

    const float* fo = first_out + (size_t)r * C_DIM;
    float e0 = fo[lane];
    int   j1 = lane + 64;
    float e1 = (j1 < C_DIM) ? fo[j1] : -INFINITY;

    float v1, v2; int i1, i2;
    if (vi_gt(e1, j1, e0, lane)) { v1 = e1; i1 = j1;   v2 = e0; i2 = lane; }
    else                         { v1 = e0; i1 = lane; v2 = e1; i2 = j1; }

    #pragma unroll
    for (int m = 1; m < 64; m <<= 1) {
        float ov1 = __shfl_xor(v1, m, 64);
        int   oi1 = __shfl_xor(i1, m, 64);
        float ov2 = __shfl_xor(v2, m, 64);
        int   oi2 = __shfl_xor(i2, m, 64);
        if (vi_gt(ov1, oi1, v1, i1)) {
            float nv2; int ni2;
            if (vi_gt(v1, i1, ov2, oi2)) { nv2 = v1;  ni2 = i1; }
            else                         { nv2 = ov2; ni2 = oi2; }
            v1 = ov1; i1 = oi1; v2 = nv2; i2 = ni2;
        } else {
            if (vi_gt(ov1, oi1, v2, i2)) { v2 = ov1; i2 = oi1; }
        }
    }
    if (lane == 0) {
        const int a = min(i1, i2);
        const int b = max(i1, i2);
        abbuf[r] = a | (b << 16);
    }
}

// ---------------- K3: dots + logits + argmax ----------------
__global__ __launch_bounds__(256) void main_kernel(
    const float* __restrict__ x,
    const float* __restrict__ weights,
    const float* __restrict__ sigma,
    const double* __restrict__ invn,
    const int* __restrict__ abbuf,
    float* __restrict__ out,
    int B)
{
    const int lane = threadIdx.x & 63;
    const int r = (blockIdx.x << 2) + (threadIdx.x >> 6);
    if (r >= B) return;

    const int ab = abbuf[r];            // broadcast load (same addr per wave)
    const int a = ab & 0xffff;
    const int b = ab >> 16;
    const int pair = b * (b - 1) / 2 + a;

    const float4* xv = (const float4*)(x + (size_t)r * D_DIM);
    const float4* w0 = (const float4*)(weights + (size_t)pair * (2 * D_DIM));
    const float4* w1 = w0 + F4_PER_ROW;

    // xx in f32: common positive scale on both logits -> cannot flip argmax,
    // and adds only ~1e-7 relative error to the logits. d0/d1 stay f64.
    float  xx = 0.0f;
    double d0 = 0.0, d1 = 0.0;
    #pragma unroll
    for (int j = 0; j < 3; ++j) {
        const int idx = lane + j * 64;
        float4 xa = xv[idx];
        float4 wa = w0[idx];
        float4 wb = w1[idx];
        xx += xa.x * xa.x + xa.y * xa.y + xa.z * xa.z + xa.w * xa.w;
        d0 += (double)xa.x * wa.x + (double)xa.y * wa.y
            + (double)xa.z * wa.z + (double)xa.w * wa.w;
        d1 += (double)xa.x * wb.x + (double)xa.y * wb.y
            + (double)xa.z * wb.z + (double)xa.w * wb.w;
    }
    #pragma unroll
    for (int m = 1; m < 64; m <<= 1) {
        xx += __shfl_xor(xx, m, 64);
        d0 += __shfl_xor(d0, m, 64);
        d1 += __shfl_xor(d1, m, 64);
    }

    if (lane == 0) {
        double s    = (double)sigma[pair];
        double sinx = s / fmax(sqrt((double)xx), EPS_N);
        double l0   = sinx * d0 * invn[2 * pair];
        double l1   = sinx * d1 * invn[2 * pair + 1];
        int sel = (l1 > l0) ? 1 : 0;    // jnp.argmax: first index wins ties
        out[r] = (float)(sel ? b : a);
        out[B + 2 * r]     = (float)l0;
        out[B + 2 * r + 1] = (float)l1;
    }
}

extern "C" void kernel_launch(void* const* d_in, const int* in_sizes, int n_in,
                              void* d_out, int out_size, void* d_ws, size_t ws_size,
                              hipStream_t stream) {
    const float* x         = (const float*)d_in[0];
    const float* first_out = (const float*)d_in[1];
    const float* weights   = (const float*)d_in[2];
    const float* sigma     = (const float*)d_in[3];
    float* out = (float*)d_out;

    const int B = in_sizes[0] / D_DIM;        // 65536
    const int NW = 2 * P_DIM;                 // 9900 weight vectors

    // ws layout: [invn: 2P doubles][abbuf: B ints]  (~342 KB)
    double* invn = (double*)d_ws;
    int* abbuf   = (int*)((char*)d_ws + (size_t)NW * sizeof(double));

    hipLaunchKernelGGL(norm_kernel, dim3((NW + 3) / 4), dim3(256), 0, stream,
                       weights, invn, NW);
    hipLaunchKernelGGL(top2_kernel, dim3((B + 3) / 4), dim3(256), 0, stream,
                       first_out, abbuf, B);
    hipLaunchKernelGGL(main_kernel, dim3((B + 3) / 4), dim3(256), 0, stream,
                       x, weights, sigma, invn, abbuf, out, B);
}